// Round 7
// baseline (381.443 us; speedup 1.0000x reference)
//
#include <hip/hip_runtime.h>
#include <math.h>

#define ROW_N 512
#define N_ITERS 100
#define CTAB_N (N_ITERS + 4)   // padded: prefetch coefs[it+1] never OOB, no ternary
#define LAMBDA 10.0f

typedef float f2 __attribute__((ext_vector_type(2)));

__device__ __forceinline__ f2 splat(float s) { f2 r; r.x = s; r.y = s; return r; }
__device__ __forceinline__ f2 ffma(f2 a, f2 b, f2 c) {
    return __builtin_elementwise_fma(a, b, c);
}

// Precompute FISTA momentum coefficients coef[k] = (t_k - 1) / t_{k+1}.
__global__ void coef_kernel(float* __restrict__ coefs) {
    if (threadIdx.x == 0) {
        float t = 1.0f;
        float c = 0.0f;
        for (int k = 0; k < CTAB_N; ++k) {
            if (k < N_ITERS) {
                float t_new = 0.5f * (1.0f + sqrtf(1.0f + 4.0f * t * t));
                c = (t - 1.0f) / t_new;
                t = t_new;
            }
            coefs[k] = c;   // entries >= N_ITERS replicate last (never consumed)
        }
    }
}

// TWO rows per wave packed in float2 components (v_pk_*_f32 stencil);
// 8 elems/lane; ONE row-pair per wave (8192 waves, 2048 blocks).
// Iteration order 2..7,0,1 with on-demand dd; halo shuffles issued with
// >=interior-block slack before consumption. Momentum + clip are done
// per-COMPONENT (scalar v_med3/v_fma writing the f2 halves in place): same
// FMA-pipe cycles as pk, but no pk<->scalar register-pair marshaling movs,
// and coef stays in an SGPR.
template <bool USE_TABLE>
__global__ __launch_bounds__(256)
__attribute__((amdgpu_waves_per_eu(2, 8)))
void fista_kernel(
    const float* __restrict__ in, float* __restrict__ out,
    const float* __restrict__ coefs, int n_rows)
{
    const int pid  = (int)((blockIdx.x * 256u + threadIdx.x) >> 6); // row pair
    const int lane = (int)(threadIdx.x & 63u);
    const int n_pairs = (n_rows + 1) >> 1;
    if (pid >= n_pairs) return;

    const bool lane_lo = (lane == 0);
    const bool lane_hi = (lane == 63);

    const int r0 = pid * 2;
    const int r1 = (r0 + 1 < n_rows) ? r0 + 1 : r0;
    const float* rowA = in + (size_t)r0 * ROW_N + lane * 8;
    const float* rowB = in + (size_t)r1 * ROW_N + lane * 8;

    const float A = 1.0f / (1.0f + 16.0f * LAMBDA);   // 2*step
    const float B = LAMBDA / (1.0f + 16.0f * LAMBDA); // 2*step*lam
    const float C = 1.0f - A;
    const f2 Cv = splat(C), Av = splat(A), Bn = splat(-B), M2 = splat(-2.0f);
    const f2 Z2 = splat(0.0f);

    f2 y[8], ay[8], x[8], z[8];
    {
        const float4 a0 = *(const float4*)(rowA);
        const float4 a1 = *(const float4*)(rowA + 4);
        const float4 b0 = *(const float4*)(rowB);
        const float4 b1 = *(const float4*)(rowB + 4);
        y[0].x = a0.x; y[1].x = a0.y; y[2].x = a0.z; y[3].x = a0.w;
        y[4].x = a1.x; y[5].x = a1.y; y[6].x = a1.z; y[7].x = a1.w;
        y[0].y = b0.x; y[1].y = b0.y; y[2].y = b0.z; y[3].y = b0.w;
        y[4].y = b1.x; y[5].y = b1.y; y[6].y = b1.z; y[7].y = b1.w;
    }

    #pragma unroll 1
    for (int pass = 0; pass < 2; ++pass) {
        #pragma unroll
        for (int i = 0; i < 8; ++i) {
            ay[i] = Av * y[i];
            f2 x0;  // proj(y) = clip(y,0,y)
            x0.x = fminf(fmaxf(y[i].x, 0.0f), y[i].x);
            x0.y = fminf(fmaxf(y[i].y, 0.0f), y[i].y);
            x[i] = x0;
            z[i] = x0;
        }

        // pipeline prologue: halo for iteration 0
        f2 zm2, zm1, zp0, zp1;
        zm2.x = __shfl_up(z[6].x, 1);   zm2.y = __shfl_up(z[6].y, 1);
        zm1.x = __shfl_up(z[7].x, 1);   zm1.y = __shfl_up(z[7].y, 1);
        zp0.x = __shfl_down(z[0].x, 1); zp0.y = __shfl_down(z[0].y, 1);
        zp1.x = __shfl_down(z[1].x, 1); zp1.y = __shfl_down(z[1].y, 1);
        float coef, t = 1.0f;
        if (USE_TABLE) coef = coefs[0];
        else           coef = 0.0f;   // (t0-1)/t1 = 0

        #pragma unroll 4
        for (int it = 0; it < N_ITERS; ++it) {
            // next iteration's coef (uniform s_load, off critical path)
            float coef_next;
            if (USE_TABLE) {
                coef_next = coefs[it + 1];   // table padded; no select
            } else {
                float t_new = 0.5f + sqrtf(fmaf(t, t, 0.25f));
                coef_next = (t_new - 1.0f) / (0.5f + sqrtf(fmaf(t_new, t_new, 0.25f)));
                t = t_new;
            }

            const float cf = coef;
            // update element i given dtd inputs dd[i], dd[i+1], dd[i+2]
            auto upd = [&](int i, f2 da, f2 db, f2 dc) {
                f2 dtd = ffma(M2, db, da + dc);
                f2 u = ffma(Cv, z[i], ay[i]);
                u = ffma(Bn, dtd, u);
                // clip + momentum per component: scalar med3/fma write the
                // f2 halves in place (same FMA cycles, no pair marshaling)
                float xl = __builtin_amdgcn_fmed3f(u.x, 0.0f, y[i].x);
                float xh = __builtin_amdgcn_fmed3f(u.y, 0.0f, y[i].y);
                z[i].x = fmaf(cf, xl - x[i].x, xl);
                z[i].y = fmaf(cf, xh - x[i].y, xh);
                x[i].x = xl;
                x[i].y = xh;
            };

            // interior dd from OLD z (dd2,dd3 stay live for upd(0),upd(1))
            f2 dd2 = ffma(M2, z[1], z[0] + z[2]);
            f2 dd3 = ffma(M2, z[2], z[1] + z[3]);
            f2 dd4 = ffma(M2, z[3], z[2] + z[4]);
            f2 dd5 = ffma(M2, z[4], z[3] + z[5]);
            f2 dd6 = ffma(M2, z[5], z[4] + z[6]);
            f2 dd7 = ffma(M2, z[6], z[5] + z[7]);

            upd(2, dd2, dd3, dd4);
            upd(3, dd3, dd4, dd5);
            upd(4, dd4, dd5, dd6);
            upd(5, dd5, dd6, dd7);

            // down-halo dd (z6,z7 still old); zp0/zp1 from prev iter's end
            f2 dd8 = ffma(M2, z[7], z[6] + zp0);
            f2 dd9 = ffma(M2, zp0, z[7] + zp1);
            if (lane_hi) { dd8 = Z2; dd9 = Z2; }  // d undefined past n-3

            upd(6, dd6, dd7, dd8);
            upd(7, dd7, dd8, dd9);

            // issue next iter's UP halo now (new z6,z7); consumed at next dd0
            f2 nzm2, nzm1;
            nzm2.x = __shfl_up(z[6].x, 1); nzm2.y = __shfl_up(z[6].y, 1);
            nzm1.x = __shfl_up(z[7].x, 1); nzm1.y = __shfl_up(z[7].y, 1);

            // up-halo dd (z0,z1 still old; zm2,zm1 are THIS iter's halo)
            f2 dd0 = ffma(M2, zm1, zm2 + z[0]);
            f2 dd1 = ffma(M2, z[0], zm1 + z[1]);
            if (lane_lo) { dd0 = Z2; dd1 = Z2; }  // d undefined below 0

            upd(0, dd0, dd1, dd2);
            upd(1, dd1, dd2, dd3);

            // issue next iter's DOWN halo (new z0,z1); consumed at next dd8
            zp0.x = __shfl_down(z[0].x, 1); zp0.y = __shfl_down(z[0].y, 1);
            zp1.x = __shfl_down(z[1].x, 1); zp1.y = __shfl_down(z[1].y, 1);

            zm2 = nzm2; zm1 = nzm1;  // renamed away by unrolling
            coef = coef_next;
        }

        #pragma unroll
        for (int i = 0; i < 8; ++i) y[i] = x[i];  // pass 2: y = pass-1 x
    }

    float* orowA = out + (size_t)r0 * ROW_N + lane * 8;
    *(float4*)(orowA)     = make_float4(x[0].x, x[1].x, x[2].x, x[3].x);
    *(float4*)(orowA + 4) = make_float4(x[4].x, x[5].x, x[6].x, x[7].x);
    if (r1 > r0) {
        float* orowB = out + (size_t)r1 * ROW_N + lane * 8;
        *(float4*)(orowB)     = make_float4(x[0].y, x[1].y, x[2].y, x[3].y);
        *(float4*)(orowB + 4) = make_float4(x[4].y, x[5].y, x[6].y, x[7].y);
    }
}

extern "C" void kernel_launch(void* const* d_in, const int* in_sizes, int n_in,
                              void* d_out, int out_size, void* d_ws, size_t ws_size,
                              hipStream_t stream) {
    const float* in = (const float*)d_in[0];
    float* out = (float*)d_out;

    const int total   = in_sizes[0];
    const int n_rows  = total / ROW_N;          // 16384
    const int n_pairs = (n_rows + 1) >> 1;      // 8192 waves, 1 pair/wave
    const int waves_per_block = 4;              // 256 threads
    const int blocks = (n_pairs + waves_per_block - 1) / waves_per_block;

    if (ws_size >= CTAB_N * sizeof(float)) {
        float* coefs = (float*)d_ws;
        coef_kernel<<<1, 64, 0, stream>>>(coefs);
        fista_kernel<true><<<blocks, 256, 0, stream>>>(in, out, coefs, n_rows);
    } else {
        fista_kernel<false><<<blocks, 256, 0, stream>>>(in, out, nullptr, n_rows);
    }
}

// Round 9
// 363.388 us; speedup vs baseline: 1.0497x; 1.0497x over previous
//
#include <hip/hip_runtime.h>
#include <math.h>

#define ROW_N 512
#define N_ITERS 100
#define CTAB_N (N_ITERS + 4)   // padded: coefs[it+1] never OOB, no select
#define LAMBDA 10.0f

typedef float f2 __attribute__((ext_vector_type(2)));

__device__ __forceinline__ f2 splat(float s) { f2 r; r.x = s; r.y = s; return r; }
__device__ __forceinline__ f2 ffma(f2 a, f2 b, f2 c) {
    return __builtin_elementwise_fma(a, b, c);
}

// Precompute FISTA momentum coefficients coef[k] = (t_k - 1) / t_{k+1}.
__global__ void coef_kernel(float* __restrict__ coefs) {
    if (threadIdx.x == 0) {
        float t = 1.0f;
        float c = 0.0f;
        for (int k = 0; k < CTAB_N; ++k) {
            if (k < N_ITERS) {
                float t_new = 0.5f * (1.0f + sqrtf(1.0f + 4.0f * t * t));
                c = (t - 1.0f) / t_new;
                t = t_new;
            }
            coefs[k] = c;
        }
    }
}

// R6 structure + fused direct 5-point stencil:
//   u_k = ay_k + (C-6B) z_k + 4B (z_{k-1}+z_{k+1}) - B (z_{k-2}+z_{k+2})
// replaces the two-stage dd/dtd evaluation (52 -> 40 pk ops/iter).
// DtD boundary rows (k in {0,1,n-2,n-1}):
//   row 0    : [ 1,-2, 1]          -> u = ay + (C-B) z0 + 2B z1 - B z2
//   row 1    : [-2, 5,-4, 1]       -> u = ay + (C-5B)z1 + 2B z0 + 4B z2 - B z3
//   row n-2  : [ 1,-4, 5,-2] (mir) -> u = ay + (C-5B)z6 + 4B z5 + 2B z7 - B z4
//   row n-1  : [ 1,-2, 1]   (mir)  -> u = ay + (C-B) z7 + 2B z6 - B z5
// folded into 6 lane-selected coefficient regs (cndmask once, pre-loop) +
// per-iter halo zeroing (same cndmask count as R6's dd zeroing).
template <bool USE_TABLE>
__global__ __launch_bounds__(256)
__attribute__((amdgpu_waves_per_eu(2, 8)))
void fista_kernel(
    const float* __restrict__ in, float* __restrict__ out,
    const float* __restrict__ coefs, int n_rows)
{
    const int pid  = (int)((blockIdx.x * 256u + threadIdx.x) >> 6); // row pair
    const int lane = (int)(threadIdx.x & 63u);
    const int n_pairs = (n_rows + 1) >> 1;
    if (pid >= n_pairs) return;

    const bool lane_lo = (lane == 0);
    const bool lane_hi = (lane == 63);

    const int r0 = pid * 2;
    const int r1 = (r0 + 1 < n_rows) ? r0 + 1 : r0;
    const float* rowA = in + (size_t)r0 * ROW_N + lane * 8;
    const float* rowB = in + (size_t)r1 * ROW_N + lane * 8;

    const float A = 1.0f / (1.0f + 16.0f * LAMBDA);   // 2*step
    const float B = LAMBDA / (1.0f + 16.0f * LAMBDA); // 2*step*lam
    const float C = 1.0f - A;
    const f2 Av = splat(A);
    const f2 C6 = splat(C - 6.0f * B);
    const f2 B4 = splat(4.0f * B);
    const f2 Bm = splat(-B);
    const f2 Z2 = splat(0.0f);

    // lane-dependent boundary coefficients (set once; cndmask'd)
    const f2 cz0   = lane_lo ? splat(C - B)        : C6;
    const f2 cz1   = lane_lo ? splat(C - 5.0f * B) : C6;
    const f2 ca_lo = lane_lo ? splat(2.0f * B)     : B4;
    const f2 cz6   = lane_hi ? splat(C - 5.0f * B) : C6;
    const f2 cz7   = lane_hi ? splat(C - B)        : C6;
    const f2 ca_hi = lane_hi ? splat(2.0f * B)     : B4;

    f2 y[8], ay[8], x[8], z[8];
    {
        const float4 a0 = *(const float4*)(rowA);
        const float4 a1 = *(const float4*)(rowA + 4);
        const float4 b0 = *(const float4*)(rowB);
        const float4 b1 = *(const float4*)(rowB + 4);
        y[0].x = a0.x; y[1].x = a0.y; y[2].x = a0.z; y[3].x = a0.w;
        y[4].x = a1.x; y[5].x = a1.y; y[6].x = a1.z; y[7].x = a1.w;
        y[0].y = b0.x; y[1].y = b0.y; y[2].y = b0.z; y[3].y = b0.w;
        y[4].y = b1.x; y[5].y = b1.y; y[6].y = b1.z; y[7].y = b1.w;
    }

    #pragma unroll 1
    for (int pass = 0; pass < 2; ++pass) {
        #pragma unroll
        for (int i = 0; i < 8; ++i) {
            ay[i] = Av * y[i];
            f2 x0;  // proj(y) = clip(y,0,y)
            x0.x = fminf(fmaxf(y[i].x, 0.0f), y[i].x);
            x0.y = fminf(fmaxf(y[i].y, 0.0f), y[i].y);
            x[i] = x0;
            z[i] = x0;
        }

        // pipeline prologue: halo for iteration 0
        f2 zm2, zm1, zp0, zp1;
        zm2.x = __shfl_up(z[6].x, 1);   zm2.y = __shfl_up(z[6].y, 1);
        zm1.x = __shfl_up(z[7].x, 1);   zm1.y = __shfl_up(z[7].y, 1);
        zp0.x = __shfl_down(z[0].x, 1); zp0.y = __shfl_down(z[0].y, 1);
        zp1.x = __shfl_down(z[1].x, 1); zp1.y = __shfl_down(z[1].y, 1);
        float coef, t = 1.0f;
        if (USE_TABLE) coef = coefs[0];
        else           coef = 0.0f;   // (t0-1)/t1 = 0

        #pragma unroll 2
        for (int it = 0; it < N_ITERS; ++it) {
            // next iteration's coef (uniform s_load, off critical path)
            float coef_next;
            if (USE_TABLE) {
                coef_next = coefs[it + 1];   // padded table
            } else {
                float t_new = 0.5f + sqrtf(fmaf(t, t, 0.25f));
                coef_next = (t_new - 1.0f) / (0.5f + sqrtf(fmaf(t_new, t_new, 0.25f)));
                t = t_new;
            }

            const f2 cf = splat(coef);
            // clip + momentum, given the gradient-step value u
            auto fin = [&](int i, f2 u) {
                f2 xn;
                xn.x = __builtin_amdgcn_fmed3f(u.x, 0.0f, y[i].x); // clip(u,0,y)
                xn.y = __builtin_amdgcn_fmed3f(u.y, 0.0f, y[i].y);
                z[i] = ffma(cf, xn - x[i], xn);
                x[i] = xn;
            };

            // 1. zero out-of-row halos (boundary rows of DtD have no outside terms)
            if (lane_lo) { zm2 = Z2; zm1 = Z2; }
            if (lane_hi) { zp0 = Z2; zp1 = Z2; }

            // 2. edge neighbor sums (ALL read old z)
            f2 ta0 = zm1 + z[1];
            f2 tb0 = zm2 + z[2];
            f2 tb1 = zm1 + z[3];
            f2 tb6 = z[4] + zp0;
            f2 ta7 = z[6] + zp0;
            f2 tb7 = z[5] + zp1;

            // 3. edge u chains (all reads of old z happen here)
            f2 u0 = ffma(cz0, z[0], ay[0]);
            u0 = ffma(ca_lo, ta0, u0);
            u0 = ffma(Bm, tb0, u0);
            f2 u1 = ffma(cz1, z[1], ay[1]);
            u1 = ffma(ca_lo, z[0], u1);
            u1 = ffma(B4, z[2], u1);
            u1 = ffma(Bm, tb1, u1);
            f2 u6 = ffma(cz6, z[6], ay[6]);
            u6 = ffma(B4, z[5], u6);
            u6 = ffma(ca_hi, z[7], u6);
            u6 = ffma(Bm, tb6, u6);
            f2 u7 = ffma(cz7, z[7], ay[7]);
            u7 = ffma(ca_hi, ta7, u7);
            u7 = ffma(Bm, tb7, u7);

            // 4. interior neighbor sums (old z)
            f2 ta2 = z[1] + z[3], tb2 = z[0] + z[4];
            f2 ta3 = z[2] + z[4], tb3 = z[1] + z[5];
            f2 ta4 = z[3] + z[5], tb4 = z[2] + z[6];
            f2 ta5 = z[4] + z[6], tb5 = z[3] + z[7];

            // 5. update edges 6,7 -> issue next iter's UP halo
            fin(6, u6);
            fin(7, u7);
            f2 nzm2, nzm1;
            nzm2.x = __shfl_up(z[6].x, 1); nzm2.y = __shfl_up(z[6].y, 1);
            nzm1.x = __shfl_up(z[7].x, 1); nzm1.y = __shfl_up(z[7].y, 1);

            // 6. update edges 0,1 -> issue next iter's DOWN halo
            fin(0, u0);
            fin(1, u1);
            f2 nzp0, nzp1;
            nzp0.x = __shfl_down(z[0].x, 1); nzp0.y = __shfl_down(z[0].y, 1);
            nzp1.x = __shfl_down(z[1].x, 1); nzp1.y = __shfl_down(z[1].y, 1);

            // 7. interior chains + updates (covers shuffle latency)
            f2 u2 = ffma(C6, z[2], ay[2]);
            u2 = ffma(B4, ta2, u2);
            u2 = ffma(Bm, tb2, u2);
            fin(2, u2);
            f2 u3 = ffma(C6, z[3], ay[3]);
            u3 = ffma(B4, ta3, u3);
            u3 = ffma(Bm, tb3, u3);
            fin(3, u3);
            f2 u4 = ffma(C6, z[4], ay[4]);
            u4 = ffma(B4, ta4, u4);
            u4 = ffma(Bm, tb4, u4);
            fin(4, u4);
            f2 u5 = ffma(C6, z[5], ay[5]);
            u5 = ffma(B4, ta5, u5);
            u5 = ffma(Bm, tb5, u5);
            fin(5, u5);

            zm2 = nzm2; zm1 = nzm1; zp0 = nzp0; zp1 = nzp1;
            coef = coef_next;
        }

        #pragma unroll
        for (int i = 0; i < 8; ++i) y[i] = x[i];  // pass 2: y = pass-1 x
    }

    float* orowA = out + (size_t)r0 * ROW_N + lane * 8;
    *(float4*)(orowA)     = make_float4(x[0].x, x[1].x, x[2].x, x[3].x);
    *(float4*)(orowA + 4) = make_float4(x[4].x, x[5].x, x[6].x, x[7].x);
    if (r1 > r0) {
        float* orowB = out + (size_t)r1 * ROW_N + lane * 8;
        *(float4*)(orowB)     = make_float4(x[0].y, x[1].y, x[2].y, x[3].y);
        *(float4*)(orowB + 4) = make_float4(x[4].y, x[5].y, x[6].y, x[7].y);
    }
}

extern "C" void kernel_launch(void* const* d_in, const int* in_sizes, int n_in,
                              void* d_out, int out_size, void* d_ws, size_t ws_size,
                              hipStream_t stream) {
    const float* in = (const float*)d_in[0];
    float* out = (float*)d_out;

    const int total   = in_sizes[0];
    const int n_rows  = total / ROW_N;          // 16384
    const int n_pairs = (n_rows + 1) >> 1;      // 8192 waves, 1 pair/wave
    const int waves_per_block = 4;              // 256 threads
    const int blocks = (n_pairs + waves_per_block - 1) / waves_per_block;

    if (ws_size >= CTAB_N * sizeof(float)) {
        float* coefs = (float*)d_ws;
        coef_kernel<<<1, 64, 0, stream>>>(coefs);
        fista_kernel<true><<<blocks, 256, 0, stream>>>(in, out, coefs, n_rows);
    } else {
        fista_kernel<false><<<blocks, 256, 0, stream>>>(in, out, nullptr, n_rows);
    }
}